// Round 10
// baseline (124.016 us; speedup 1.0000x reference)
//
#include <hip/hip_runtime.h>

// Problem constants
constexpr int N_NODES  = 50000;
constexpr int C_IN     = 128;
constexpr int C_OUT    = 128;
constexpr int E_EDGES  = 250000;
constexpr int G_GRP    = 4;
constexpr int NXCD     = 8;
constexpr int CAP      = 32;    // bucket storage per node (max deg <=32 proven R4)
constexpr int CAP1     = 8;     // unconditional slots
constexpr int TMF      = 64;    // rows per fused block

// Collapsed math (softmax rows sum to 1 => group structure cancels):
//   out[n] = x[n]@W_self + (sum_{edges s->n} x[s])@W_nbr + G*b

typedef __attribute__((ext_vector_type(8))) short     short8;  // 8 bf16
typedef __attribute__((ext_vector_type(4))) float     f32x4;
typedef __attribute__((ext_vector_type(2))) unsigned  u32x2;
typedef __attribute__((ext_vector_type(4))) unsigned  u32x4;

__device__ __forceinline__ unsigned short f2bf(float f) {
    unsigned u = __builtin_bit_cast(unsigned, f);
    u += 0x7fffu + ((u >> 16) & 1u);
    return (unsigned short)(u >> 16);
}
__device__ __forceinline__ unsigned pack2(float lo, float hi) {
    return (unsigned)f2bf(lo) | ((unsigned)f2bf(hi) << 16);
}
__device__ __forceinline__ float bflo(unsigned u) {
    return __builtin_bit_cast(float, u << 16);
}
__device__ __forceinline__ float bfhi(unsigned u) {
    return __builtin_bit_cast(float, u & 0xffff0000u);
}
__device__ __forceinline__ int xcd_swizzle(int bid, int nblocks) {
    int q = nblocks / NXCD, r = nblocks % NXCD;
    int xcd = bid % NXCD, lid = bid / NXCD;
    return (xcd < r ? xcd * (q + 1) : r * (q + 1) + (xcd - r) * q) + lid;
}

// -------------------------------------------------------------------------
// Dispatch 1: zero cnt | build WT (bf16 transposed) | convert x -> xb (bf16)
// -------------------------------------------------------------------------
constexpr int CNT_BLKS = (N_NODES / 4 + 255) / 256;         // 49
constexpr int WT_BLKS  = (C_OUT * 256) / 256;               // 128
constexpr int XB_BLKS  = (N_NODES * 16) / 256;              // 3125

__global__ __launch_bounds__(256) void prep_kernel(
    int* __restrict__ cnt,
    const float* __restrict__ Wself, const float* __restrict__ Wnbr,
    unsigned short* __restrict__ WT,
    const float* __restrict__ x, unsigned short* __restrict__ xb)
{
    int b = blockIdx.x;
    if (b < CNT_BLKS) {
        int idx = b * 256 + threadIdx.x;
        if (idx < N_NODES / 4)
            reinterpret_cast<int4*>(cnt)[idx] = make_int4(0, 0, 0, 0);
    } else if (b < CNT_BLKS + WT_BLKS) {
        int idx = (b - CNT_BLKS) * 256 + threadIdx.x;
        int c = idx >> 8, k = idx & 255;
        float v = (k < 128) ? Wself[k * C_OUT + c] : Wnbr[(k - 128) * C_OUT + c];
        WT[idx] = f2bf(v);
    } else {
        int idx = (b - CNT_BLKS - WT_BLKS) * 256 + threadIdx.x;
        const float4* xp = reinterpret_cast<const float4*>(x) + (size_t)idx * 2;
        float4 v0 = xp[0], v1 = xp[1];
        u32x4 o{pack2(v0.x, v0.y), pack2(v0.z, v0.w),
                pack2(v1.x, v1.y), pack2(v1.z, v1.w)};
        reinterpret_cast<u32x4*>(xb)[idx] = o;
    }
}

// -------------------------------------------------------------------------
// Dispatch 2: fill buckets
// -------------------------------------------------------------------------
constexpr int EDGE_BLOCKS = (E_EDGES + 255) / 256;          // 977

__global__ __launch_bounds__(256) void fill_kernel(
    const int* __restrict__ src, const int* __restrict__ dst,
    int* __restrict__ cnt, int* __restrict__ buckets)
{
    int e = blockIdx.x * 256 + threadIdx.x;
    if (e < E_EDGES) {
        int d = dst[e];
        int pos = atomicAdd(&cnt[d], 1);
        if (pos < CAP) buckets[(size_t)d * CAP + pos] = src[e];
    }
}

// -------------------------------------------------------------------------
// Fused kernel, ABLATION-TEMPLATED (rocprof per-dispatch rows attribute):
//   V=0 full (stage + gather + MFMA -> out)          [identical to R9]
//   V=1 stage + MFMA only, gather zeroed -> scr      (GEMM-phase cost)
//   V=2 gather only -> scr                           (gather-phase cost)
// -------------------------------------------------------------------------
constexpr int FUSED_BLOCKS = (N_NODES + TMF - 1) / TMF;     // 782

template<int V>
__global__ __launch_bounds__(512) void fused_kernel(
    const unsigned short* __restrict__ xb,
    const int* __restrict__ cnt,
    const int* __restrict__ buckets,
    const unsigned short* __restrict__ WT,
    const float* __restrict__ bias,
    float* __restrict__ out,
    u32x2* __restrict__ xa_scr)
{
    __shared__ unsigned char Ab[TMF * 512];     // 32 KB

    int wg = xcd_swizzle(blockIdx.x, FUSED_BLOCKS);
    const int tid  = threadIdx.x;
    const int row0 = wg * TMF;

    // ---- stage x rows (k = 0..127): straight bf16 copy from xb ----
    if constexpr (V != 2) {
        #pragma unroll
        for (int i = 0; i < 4; ++i) {
            int idx = tid + i * 512;
            int r = idx >> 5, q = idx & 31;
            int n = row0 + r;
            u32x2 pk{0u, 0u};
            if (n < N_NODES)
                pk = *reinterpret_cast<const u32x2*>(&xb[(size_t)n * 128 + q * 4]);
            int byte = (r * 512 + q * 8) ^ ((r & 7) << 4);
            *reinterpret_cast<u32x2*>(&Ab[byte]) = pk;
        }
    }

    // ---- gather phase (V0: ->LDS; V2: ->scratch; V1: zeros ->LDS) ----
    if constexpr (V == 1) {
        const int slot = tid >> 5;
        const int q    = tid & 31;
        #pragma unroll
        for (int h = 0; h < 4; ++h) {
            int r = slot + h * 16;
            int byte = (r * 512 + 256 + q * 8) ^ ((r & 7) << 4);
            *reinterpret_cast<u32x2*>(&Ab[byte]) = u32x2{0u, 0u};
        }
    } else {
        const int slot = tid >> 5;
        const int q    = tid & 31;
        const u32x2* xb2 = reinterpret_cast<const u32x2*>(xb);
        #pragma unroll
        for (int h = 0; h < 4; ++h) {
            int r  = slot + h * 16;
            int n  = row0 + r;
            int nc = (n < N_NODES) ? n : (N_NODES - 1);
            int d  = cnt[nc];
            if (d > CAP) d = CAP;
            if (n >= N_NODES) d = 0;
            const int4* sp4 = reinterpret_cast<const int4*>(buckets + (size_t)nc * CAP);

            float a0 = 0.f, a1 = 0.f, a2 = 0.f, a3 = 0.f;
            {
                int4 sA = sp4[0], sB = sp4[1];
                int s0 = (0 < d) ? sA.x : 0, s1 = (1 < d) ? sA.y : 0;
                int s2 = (2 < d) ? sA.z : 0, s3 = (3 < d) ? sA.w : 0;
                int s4 = (4 < d) ? sB.x : 0, s5 = (5 < d) ? sB.y : 0;
                int s6 = (6 < d) ? sB.z : 0, s7 = (7 < d) ? sB.w : 0;
                u32x2 w0 = xb2[(size_t)s0 * 32 + q];
                u32x2 w1 = xb2[(size_t)s1 * 32 + q];
                u32x2 w2 = xb2[(size_t)s2 * 32 + q];
                u32x2 w3 = xb2[(size_t)s3 * 32 + q];
                u32x2 w4 = xb2[(size_t)s4 * 32 + q];
                u32x2 w5 = xb2[(size_t)s5 * 32 + q];
                u32x2 w6 = xb2[(size_t)s6 * 32 + q];
                u32x2 w7 = xb2[(size_t)s7 * 32 + q];
                #define ACC(W, K)                                               \
                    { float m = (K < d) ? 1.f : 0.f;                            \
                      a0 = fmaf(m, bflo(W.x), a0); a1 = fmaf(m, bfhi(W.x), a1); \
                      a2 = fmaf(m, bflo(W.y), a2); a3 = fmaf(m, bfhi(W.y), a3); }
                ACC(w0, 0) ACC(w1, 1) ACC(w2, 2) ACC(w3, 3)
                ACC(w4, 4) ACC(w5, 5) ACC(w6, 6) ACC(w7, 7)
            }
            if (d > CAP1) {
                #pragma unroll
                for (int t = 0; t < 3; ++t) {
                    int4 sC = sp4[2 + 2 * t], sD = sp4[3 + 2 * t];
                    int base = 8 + t * 8;
                    int s0 = (base + 0 < d) ? sC.x : 0, s1 = (base + 1 < d) ? sC.y : 0;
                    int s2 = (base + 2 < d) ? sC.z : 0, s3 = (base + 3 < d) ? sC.w : 0;
                    int s4 = (base + 4 < d) ? sD.x : 0, s5 = (base + 5 < d) ? sD.y : 0;
                    int s6 = (base + 6 < d) ? sD.z : 0, s7 = (base + 7 < d) ? sD.w : 0;
                    u32x2 w0 = xb2[(size_t)s0 * 32 + q];
                    u32x2 w1 = xb2[(size_t)s1 * 32 + q];
                    u32x2 w2 = xb2[(size_t)s2 * 32 + q];
                    u32x2 w3 = xb2[(size_t)s3 * 32 + q];
                    u32x2 w4 = xb2[(size_t)s4 * 32 + q];
                    u32x2 w5 = xb2[(size_t)s5 * 32 + q];
                    u32x2 w6 = xb2[(size_t)s6 * 32 + q];
                    u32x2 w7 = xb2[(size_t)s7 * 32 + q];
                    #define ACC2(W, K)                                              \
                        { float m = (base + K < d) ? 1.f : 0.f;                     \
                          a0 = fmaf(m, bflo(W.x), a0); a1 = fmaf(m, bfhi(W.x), a1); \
                          a2 = fmaf(m, bflo(W.y), a2); a3 = fmaf(m, bfhi(W.y), a3); }
                    ACC2(w0, 0) ACC2(w1, 1) ACC2(w2, 2) ACC2(w3, 3)
                    ACC2(w4, 4) ACC2(w5, 5) ACC2(w6, 6) ACC2(w7, 7)
                    #undef ACC2
                }
            }
            #undef ACC
            u32x2 res{pack2(a0, a1), pack2(a2, a3)};
            if constexpr (V == 2) {
                if (n < N_NODES) xa_scr[(size_t)n * 32 + q] = res;  // live store
            } else {
                int byte = (r * 512 + 256 + q * 8) ^ ((r & 7) << 4);
                *reinterpret_cast<u32x2*>(&Ab[byte]) = res;
            }
        }
    }

    if constexpr (V == 2) return;

    __syncthreads();

    // ---- MFMA: wave w -> row-tile rt = w>>1, col-half ct0 = (w&1)*4 ----
    const int lane = tid & 63;
    const int w    = tid >> 6;
    const int rt   = w >> 1;
    const int ct0  = (w & 1) * 4;

    short8 a[8];
    {
        int r  = rt * 16 + (lane & 15);
        int kb = (lane >> 4) * 16;
        #pragma unroll
        for (int ks = 0; ks < 8; ++ks) {
            int byte = (r * 512 + ks * 64 + kb) ^ ((r & 7) << 4);
            a[ks] = *reinterpret_cast<const short8*>(&Ab[byte]);
        }
    }

    #pragma unroll
    for (int cti = 0; cti < 4; ++cti) {
        int c = (ct0 + cti) * 16 + (lane & 15);
        const short8* bp = reinterpret_cast<const short8*>(WT + (size_t)c * 256)
                           + (lane >> 4);
        f32x4 acc = {0.f, 0.f, 0.f, 0.f};
        #pragma unroll
        for (int ks = 0; ks < 8; ++ks)
            acc = __builtin_amdgcn_mfma_f32_16x16x32_bf16(a[ks], bp[ks * 4],
                                                          acc, 0, 0, 0);
        float bv = (float)G_GRP * bias[c];
        #pragma unroll
        for (int ii = 0; ii < 4; ++ii) {
            int rr = row0 + rt * 16 + (lane >> 4) * 4 + ii;
            if (rr < N_NODES) out[(size_t)rr * C_OUT + c] = acc[ii] + bv;
        }
    }
}

extern "C" void kernel_launch(void* const* d_in, const int* in_sizes, int n_in,
                              void* d_out, int out_size, void* d_ws, size_t ws_size,
                              hipStream_t stream)
{
    const float* x     = (const float*)d_in[0];
    // d_in[1] = W_group -- cancels (softmax rows sum to 1)
    const float* Wself = (const float*)d_in[2];
    const float* Wnbr  = (const float*)d_in[3];
    const float* bias  = (const float*)d_in[4];
    const int*   eidx  = (const int*)d_in[5];
    // d_in[6] = batch, d_in[7] = group_ptr -- unused after collapse

    const int* src = eidx;
    const int* dst = eidx + E_EDGES;

    // Workspace layout
    int* cnt     = (int*)d_ws;                                   // 200 KB
    int* buckets = cnt + N_NODES;                                // 6.4 MB
    unsigned short* WT = (unsigned short*)(buckets + (size_t)N_NODES * CAP); // 64 KB
    unsigned short* xb = WT + (size_t)C_OUT * 256;               // 12.8 MB
    float* scr = (float*)(xb + (size_t)N_NODES * 128);           // 25.6 MB (ablation)
    size_t needed = (size_t)N_NODES * 4 + (size_t)N_NODES * CAP * 4
                  + (size_t)C_OUT * 256 * 2 + (size_t)N_NODES * 128 * 2
                  + (size_t)N_NODES * C_OUT * 4;
    bool abl = (ws_size >= needed);       // poison showed ws ~268 MB; guard anyway

    float* out = (float*)d_out;

    prep_kernel<<<CNT_BLKS + WT_BLKS + XB_BLKS, 256, 0, stream>>>(
        cnt, Wself, Wnbr, WT, x, xb);

    fill_kernel<<<EDGE_BLOCKS, 256, 0, stream>>>(src, dst, cnt, buckets);

    if (abl) {
        // V1: stage + MFMA, no gather  (GEMM-phase cost, output -> scratch)
        fused_kernel<1><<<FUSED_BLOCKS, 512, 0, stream>>>(
            xb, cnt, buckets, WT, bias, scr, (u32x2*)scr);
        // V2: gather only (gather-phase cost, output -> scratch)
        fused_kernel<2><<<FUSED_BLOCKS, 512, 0, stream>>>(
            xb, cnt, buckets, WT, bias, scr, (u32x2*)scr);
    }

    // V0: full kernel (identical to R9), writes the real output LAST
    fused_kernel<0><<<FUSED_BLOCKS, 512, 0, stream>>>(
        xb, cnt, buckets, WT, bias, out, (u32x2*)scr);
}

// Round 11
// 90.122 us; speedup vs baseline: 1.3761x; 1.3761x over previous
//
#include <hip/hip_runtime.h>

// Problem constants
constexpr int N_NODES  = 50000;
constexpr int C_IN     = 128;
constexpr int C_OUT    = 128;
constexpr int E_EDGES  = 250000;
constexpr int G_GRP    = 4;
constexpr int NPG      = 1000;   // nodes per graph
constexpr int B_GRAPHS = 50;
constexpr int NXCD     = 8;
constexpr int CAP      = 32;     // bucket capacity (max deg << 32, Poisson(5))
constexpr int TMF      = 64;     // rows per GEMM block

// Collapsed math (softmax rows sum to 1 => group structure cancels):
//   out[n] = x[n]@W_self + (sum_{edges s->n} x[s])@W_nbr + G*b

typedef __attribute__((ext_vector_type(8))) short     short8;
typedef __attribute__((ext_vector_type(4))) float     f32x4;
typedef __attribute__((ext_vector_type(2))) unsigned  u32x2;

__device__ __forceinline__ unsigned short f2bf(float f) {
    unsigned u = __builtin_bit_cast(unsigned, f);
    u += 0x7fffu + ((u >> 16) & 1u);
    return (unsigned short)(u >> 16);
}
__device__ __forceinline__ unsigned pack2(float lo, float hi) {
    return (unsigned)f2bf(lo) | ((unsigned)f2bf(hi) << 16);
}
__device__ __forceinline__ float bflo(unsigned u) {
    return __builtin_bit_cast(float, u << 16);
}
__device__ __forceinline__ float bfhi(unsigned u) {
    return __builtin_bit_cast(float, u & 0xffff0000u);
}
__device__ __forceinline__ int xcd_swizzle(int bid, int nblocks) {
    int q = nblocks / NXCD, r = nblocks % NXCD;
    int xcd = bid % NXCD, lid = bid / NXCD;
    return (xcd < r ? xcd * (q + 1) : r * (q + 1) + (xcd - r) * q) + lid;
}

// -------------------------------------------------------------------------
// k_prep: zero cnt | build WT (bf16, transposed)
// -------------------------------------------------------------------------
constexpr int CNT_BLKS = (N_NODES / 4 + 255) / 256;         // 49
constexpr int WT_BLKS  = (C_OUT * 256) / 256;               // 128

__global__ __launch_bounds__(256) void k_prep(
    int* __restrict__ cnt,
    const float* __restrict__ Wself, const float* __restrict__ Wnbr,
    unsigned short* __restrict__ WT)
{
    int b = blockIdx.x;
    if (b < CNT_BLKS) {
        int idx = b * 256 + threadIdx.x;
        if (idx < N_NODES / 4)
            reinterpret_cast<int4*>(cnt)[idx] = make_int4(0, 0, 0, 0);
    } else {
        int idx = (b - CNT_BLKS) * 256 + threadIdx.x;       // 0..32767
        int c = idx >> 8, k = idx & 255;
        float v = (k < 128) ? Wself[k * C_OUT + c] : Wnbr[(k - 128) * C_OUT + c];
        WT[idx] = f2bf(v);
    }
}

// -------------------------------------------------------------------------
// k_fill: buckets[dst*CAP + cursor++] = src
// -------------------------------------------------------------------------
constexpr int EDGE_BLOCKS = (E_EDGES + 255) / 256;          // 977

__global__ __launch_bounds__(256) void k_fill(
    const int* __restrict__ src, const int* __restrict__ dst,
    int* __restrict__ cnt, int* __restrict__ buckets)
{
    int e = blockIdx.x * 256 + threadIdx.x;
    if (e < E_EDGES) {
        int d = dst[e];
        int pos = atomicAdd(&cnt[d], 1);
        if (pos < CAP) buckets[(size_t)d * CAP + pos] = src[e];
    }
}

// -------------------------------------------------------------------------
// k_gather: block = (graph, 16-channel octant). Stage the graph window slice
// (1000 x 16ch, f32 -> bf16) into 32KB LDS, then gather neighbor sums with
// ds_read_b32 (pipelined ~120cy, ~2-way banked) instead of scattered VMEM.
// -------------------------------------------------------------------------
constexpr int GATHER_BLOCKS = B_GRAPHS * 8;                 // 400

__global__ __launch_bounds__(512, 1) void k_gather(
    const float* __restrict__ x,
    const int* __restrict__ cnt,
    const int* __restrict__ buckets,
    unsigned short* __restrict__ xa_bf)
{
    __shared__ unsigned sxb[NPG * 8];           // [row][8 u32] bf16 pairs, 32 KB

    int b = xcd_swizzle(blockIdx.x, GATHER_BLOCKS);  // same-graph octants -> same XCD
    const int tid = threadIdx.x;
    const int g   = b >> 3;                     // graph
    const int oct = b & 7;                      // channel octant (16 ch)
    const int nb  = g * NPG;

    // ---- stage: x[nb..nb+1000)[oct*16..+16) f32 -> bf16 pairs in LDS ----
    {
        const float4* x4 = reinterpret_cast<const float4*>(x);
        for (int idx = tid; idx < NPG * 4; idx += 512) {    // 4000 float4 chunks
            int r = idx >> 2, c4 = idx & 3;
            float4 v = x4[(size_t)(nb + r) * 32 + oct * 4 + c4];
            sxb[r * 8 + c4 * 2 + 0] = pack2(v.x, v.y);
            sxb[r * 8 + c4 * 2 + 1] = pack2(v.z, v.w);
        }
    }
    __syncthreads();

    // ---- gather: 8 lanes per row (lane = u32 = 2 channels) ----
    const int ln = tid & 7;
    const int lg = tid >> 3;                    // 0..63 row groups

    for (int r = lg; r < NPG; r += 64) {
        int n = nb + r;
        int d = cnt[n];
        if (d > CAP) d = CAP;
        const int4* sp4 = reinterpret_cast<const int4*>(buckets + (size_t)n * CAP);

        float a0 = 0.f, a1 = 0.f;
        // tier 1: slots 0..7, unconditional ds_reads (clamped local row), masked fma
        {
            int4 sA = sp4[0], sB = sp4[1];
            int t0 = ((0 < d) ? sA.x : nb) - nb, t1 = ((1 < d) ? sA.y : nb) - nb;
            int t2 = ((2 < d) ? sA.z : nb) - nb, t3 = ((3 < d) ? sA.w : nb) - nb;
            int t4 = ((4 < d) ? sB.x : nb) - nb, t5 = ((5 < d) ? sB.y : nb) - nb;
            int t6 = ((6 < d) ? sB.z : nb) - nb, t7 = ((7 < d) ? sB.w : nb) - nb;
            unsigned w0 = sxb[t0 * 8 + ln], w1 = sxb[t1 * 8 + ln];
            unsigned w2 = sxb[t2 * 8 + ln], w3 = sxb[t3 * 8 + ln];
            unsigned w4 = sxb[t4 * 8 + ln], w5 = sxb[t5 * 8 + ln];
            unsigned w6 = sxb[t6 * 8 + ln], w7 = sxb[t7 * 8 + ln];
            #define ACC(W, K)                                           \
                { float m = (K < d) ? 1.f : 0.f;                        \
                  a0 = fmaf(m, bflo(W), a0); a1 = fmaf(m, bfhi(W), a1); }
            ACC(w0, 0) ACC(w1, 1) ACC(w2, 2) ACC(w3, 3)
            ACC(w4, 4) ACC(w5, 5) ACC(w6, 6) ACC(w7, 7)
            #undef ACC
        }
        // tier 2: slots 8..31, rare (P(deg>8) ~ 7%)
        if (d > 8) {
            #pragma unroll
            for (int t = 0; t < 3; ++t) {
                int base = 8 + t * 8;
                int4 sC = sp4[2 + 2 * t], sD = sp4[3 + 2 * t];
                int t0 = ((base + 0 < d) ? sC.x : nb) - nb, t1 = ((base + 1 < d) ? sC.y : nb) - nb;
                int t2 = ((base + 2 < d) ? sC.z : nb) - nb, t3 = ((base + 3 < d) ? sC.w : nb) - nb;
                int t4 = ((base + 4 < d) ? sD.x : nb) - nb, t5 = ((base + 5 < d) ? sD.y : nb) - nb;
                int t6 = ((base + 6 < d) ? sD.z : nb) - nb, t7 = ((base + 7 < d) ? sD.w : nb) - nb;
                unsigned w0 = sxb[t0 * 8 + ln], w1 = sxb[t1 * 8 + ln];
                unsigned w2 = sxb[t2 * 8 + ln], w3 = sxb[t3 * 8 + ln];
                unsigned w4 = sxb[t4 * 8 + ln], w5 = sxb[t5 * 8 + ln];
                unsigned w6 = sxb[t6 * 8 + ln], w7 = sxb[t7 * 8 + ln];
                #define ACC2(W, K)                                          \
                    { float m = (base + K < d) ? 1.f : 0.f;                 \
                      a0 = fmaf(m, bflo(W), a0); a1 = fmaf(m, bfhi(W), a1); }
                ACC2(w0, 0) ACC2(w1, 1) ACC2(w2, 2) ACC2(w3, 3)
                ACC2(w4, 4) ACC2(w5, 5) ACC2(w6, 6) ACC2(w7, 7)
                #undef ACC2
            }
        }
        // write 2 channels (4B) -> 8 lanes form a 32B segment per row
        reinterpret_cast<unsigned*>(xa_bf)[(size_t)n * 64 + oct * 8 + ln] = pack2(a0, a1);
    }
}

// -------------------------------------------------------------------------
// k_gemm: stage [x(f32->bf16) | xa_bf] in swizzled LDS A-tile, MFMA vs WT.
// -------------------------------------------------------------------------
constexpr int GEMM_BLOCKS = (N_NODES + TMF - 1) / TMF;      // 782

__global__ __launch_bounds__(512) void k_gemm(
    const float* __restrict__ x,
    const unsigned short* __restrict__ xa_bf,
    const unsigned short* __restrict__ WT,
    const float* __restrict__ bias,
    float* __restrict__ out)
{
    __shared__ unsigned char Ab[TMF * 512];     // 32 KB, XOR swizzle (r&7)<<4

    int wg = xcd_swizzle(blockIdx.x, GEMM_BLOCKS);
    const int tid  = threadIdx.x;
    const int row0 = wg * TMF;

    // stage x rows (k = 0..127): f32 -> bf16 pack
    #pragma unroll
    for (int i = 0; i < 4; ++i) {
        int idx = tid + i * 512;                // 2048 float4 chunks
        int r = idx >> 5, q = idx & 31;
        int n = row0 + r;
        float4 v = make_float4(0.f, 0.f, 0.f, 0.f);
        if (n < N_NODES) v = reinterpret_cast<const float4*>(x)[(size_t)n * 32 + q];
        int byte = (r * 512 + q * 8) ^ ((r & 7) << 4);
        *reinterpret_cast<u32x2*>(&Ab[byte]) = u32x2{pack2(v.x, v.y), pack2(v.z, v.w)};
    }
    // stage xa rows (k = 128..255): straight bf16 copy
    #pragma unroll
    for (int i = 0; i < 4; ++i) {
        int idx = tid + i * 512;                // 2048 8B chunks
        int r = idx >> 5, q = idx & 31;
        int n = row0 + r;
        u32x2 pk{0u, 0u};
        if (n < N_NODES)
            pk = *reinterpret_cast<const u32x2*>(&xa_bf[(size_t)n * 128 + q * 4]);
        int byte = (r * 512 + 256 + q * 8) ^ ((r & 7) << 4);
        *reinterpret_cast<u32x2*>(&Ab[byte]) = pk;
    }
    __syncthreads();

    const int lane = tid & 63;
    const int w    = tid >> 6;
    const int rt   = w >> 1;
    const int ct0  = (w & 1) * 4;

    short8 a[8];
    {
        int r  = rt * 16 + (lane & 15);
        int kb = (lane >> 4) * 16;
        #pragma unroll
        for (int ks = 0; ks < 8; ++ks) {
            int byte = (r * 512 + ks * 64 + kb) ^ ((r & 7) << 4);
            a[ks] = *reinterpret_cast<const short8*>(&Ab[byte]);
        }
    }

    #pragma unroll
    for (int cti = 0; cti < 4; ++cti) {
        int c = (ct0 + cti) * 16 + (lane & 15);
        const short8* bp = reinterpret_cast<const short8*>(WT + (size_t)c * 256)
                           + (lane >> 4);
        f32x4 acc = {0.f, 0.f, 0.f, 0.f};
        #pragma unroll
        for (int ks = 0; ks < 8; ++ks)
            acc = __builtin_amdgcn_mfma_f32_16x16x32_bf16(a[ks], bp[ks * 4],
                                                          acc, 0, 0, 0);
        float bv = (float)G_GRP * bias[c];
        #pragma unroll
        for (int ii = 0; ii < 4; ++ii) {
            int rr = row0 + rt * 16 + (lane >> 4) * 4 + ii;   // C/D row map (verified)
            if (rr < N_NODES) out[(size_t)rr * C_OUT + c] = acc[ii] + bv;
        }
    }
}

extern "C" void kernel_launch(void* const* d_in, const int* in_sizes, int n_in,
                              void* d_out, int out_size, void* d_ws, size_t ws_size,
                              hipStream_t stream)
{
    const float* x     = (const float*)d_in[0];
    // d_in[1] = W_group -- cancels (softmax rows sum to 1)
    const float* Wself = (const float*)d_in[2];
    const float* Wnbr  = (const float*)d_in[3];
    const float* bias  = (const float*)d_in[4];
    const int*   eidx  = (const int*)d_in[5];
    // d_in[6] = batch, d_in[7] = group_ptr -- unused after collapse

    const int* src = eidx;
    const int* dst = eidx + E_EDGES;

    // Workspace: cnt[N] + buckets[N*CAP] + WT[32768] u16 + xa_bf[N*128] u16
    int* cnt     = (int*)d_ws;
    int* buckets = cnt + N_NODES;
    unsigned short* WT    = (unsigned short*)(buckets + (size_t)N_NODES * CAP);
    unsigned short* xa_bf = WT + (size_t)C_OUT * 256;

    float* out = (float*)d_out;

    k_prep<<<CNT_BLKS + WT_BLKS, 256, 0, stream>>>(cnt, Wself, Wnbr, WT);

    k_fill<<<EDGE_BLOCKS, 256, 0, stream>>>(src, dst, cnt, buckets);

    k_gather<<<GATHER_BLOCKS, 512, 0, stream>>>(x, cnt, buckets, xa_bf);

    k_gemm<<<GEMM_BLOCKS, 512, 0, stream>>>(x, xa_bf, WT, bias, out);
}

// Round 12
// 74.453 us; speedup vs baseline: 1.6657x; 1.2105x over previous
//
#include <hip/hip_runtime.h>

// Problem constants
constexpr int N_NODES  = 50000;
constexpr int C_IN     = 128;
constexpr int C_OUT    = 128;
constexpr int E_EDGES  = 250000;
constexpr int G_GRP    = 4;
constexpr int NPG      = 1000;   // nodes per graph
constexpr int B_GRAPHS = 50;
constexpr int NXCD     = 8;
constexpr int CAP      = 32;     // bucket capacity (max deg << 32, Poisson(5))

// Collapsed math (softmax rows sum to 1 => group structure cancels):
//   out[n] = x[n]@W_self + (sum_{edges s->n} x[s])@W_nbr + G*b
// GEMM form: out = A @ Wcat,  A = [x | xa] (N x 256), Wcat = [Wself; Wnbr]

typedef __attribute__((ext_vector_type(8))) short     short8;
typedef __attribute__((ext_vector_type(4))) float     f32x4;
typedef __attribute__((ext_vector_type(2))) unsigned  u32x2;

__device__ __forceinline__ unsigned short f2bf(float f) {
    unsigned u = __builtin_bit_cast(unsigned, f);
    u += 0x7fffu + ((u >> 16) & 1u);
    return (unsigned short)(u >> 16);
}
__device__ __forceinline__ unsigned pack2(float lo, float hi) {
    return (unsigned)f2bf(lo) | ((unsigned)f2bf(hi) << 16);
}
__device__ __forceinline__ float bflo(unsigned u) {
    return __builtin_bit_cast(float, u << 16);
}
__device__ __forceinline__ float bfhi(unsigned u) {
    return __builtin_bit_cast(float, u & 0xffff0000u);
}
__device__ __forceinline__ int xcd_swizzle(int bid, int nblocks) {
    int q = nblocks / NXCD, r = nblocks % NXCD;
    int xcd = bid % NXCD, lid = bid / NXCD;
    return (xcd < r ? xcd * (q + 1) : r * (q + 1) + (xcd - r) * q) + lid;
}

// -------------------------------------------------------------------------
// k_zero: zero cnt (must precede k_fill; separate dispatch for ordering)
// -------------------------------------------------------------------------
constexpr int CNT_BLKS = (N_NODES / 4 + 255) / 256;         // 49

__global__ __launch_bounds__(256) void k_zero(int* __restrict__ cnt)
{
    int idx = blockIdx.x * 256 + threadIdx.x;
    if (idx < N_NODES / 4)
        reinterpret_cast<int4*>(cnt)[idx] = make_int4(0, 0, 0, 0);
}

// -------------------------------------------------------------------------
// k_fill_prep: fill buckets (edge blocks) + build WT bf16 transposed (tail)
// -------------------------------------------------------------------------
constexpr int EDGE_BLOCKS = (E_EDGES + 255) / 256;          // 977
constexpr int WT_BLKS     = (C_OUT * 256) / 256;            // 128

__global__ __launch_bounds__(256) void k_fill_prep(
    const int* __restrict__ src, const int* __restrict__ dst,
    int* __restrict__ cnt, int* __restrict__ buckets,
    const float* __restrict__ Wself, const float* __restrict__ Wnbr,
    unsigned short* __restrict__ WT)
{
    int b = blockIdx.x;
    if (b < EDGE_BLOCKS) {
        int e = b * 256 + threadIdx.x;
        if (e < E_EDGES) {
            int d = dst[e];
            int pos = atomicAdd(&cnt[d], 1);
            if (pos < CAP) buckets[(size_t)d * CAP + pos] = src[e];
        }
    } else {
        int idx = (b - EDGE_BLOCKS) * 256 + threadIdx.x;    // 0..32767
        int c = idx >> 8, k = idx & 255;
        float v = (k < 128) ? Wself[k * C_OUT + c] : Wnbr[(k - 128) * C_OUT + c];
        WT[idx] = f2bf(v);
    }
}

// -------------------------------------------------------------------------
// k_gather: block = (graph, 16-ch octant, row-quarter). Stage the graph's
// window slice (1000 x 16ch f32 -> bf16) into 32KB LDS, gather via ds_read.
// 1600 blocks, 32KB LDS -> up to 5 blocks/CU: TLP hides the slot-load latency.
// -------------------------------------------------------------------------
constexpr int GATHER_BLOCKS = B_GRAPHS * 8 * 4;             // 1600
constexpr int RPQ           = NPG / 4;                      // 250 rows/quarter

__global__ __launch_bounds__(512) void k_gather(
    const float* __restrict__ x,
    const int* __restrict__ cnt,
    const int* __restrict__ buckets,
    unsigned short* __restrict__ xa_bf)
{
    __shared__ unsigned sxb[NPG * 8];           // [row][8 u32] bf16 pairs, 32 KB

    int wg = xcd_swizzle(blockIdx.x, GATHER_BLOCKS);  // same-graph blocks -> same XCD
    const int tid = threadIdx.x;
    const int g   = wg >> 5;                    // graph (32 blocks per graph)
    const int oct = (wg >> 2) & 7;              // channel octant (16 ch)
    const int qtr = wg & 3;                     // row quarter
    const int nb  = g * NPG;

    // ---- stage: x[nb..nb+1000)[oct*16..+16) f32 -> bf16 pairs in LDS ----
    {
        const float4* x4 = reinterpret_cast<const float4*>(x);
        for (int idx = tid; idx < NPG * 4; idx += 512) {    // 4000 float4 chunks
            int r = idx >> 2, c4 = idx & 3;
            float4 v = x4[(size_t)(nb + r) * 32 + oct * 4 + c4];
            sxb[r * 8 + c4 * 2 + 0] = pack2(v.x, v.y);
            sxb[r * 8 + c4 * 2 + 1] = pack2(v.z, v.w);
        }
    }
    __syncthreads();

    // ---- gather: 8 lanes per row (lane = u32 = 2 channels), 4 iterations ----
    const int ln = tid & 7;
    const int lg = tid >> 3;                    // 0..63 row groups

    #pragma unroll
    for (int i = 0; i < 4; ++i) {
        int rl = lg + i * 64;                   // 0..255 local-in-quarter
        if (rl >= RPQ) break;
        int r = qtr * RPQ + rl;
        int n = nb + r;
        int d = cnt[n];
        if (d > CAP) d = CAP;
        const int4* sp4 = reinterpret_cast<const int4*>(buckets + (size_t)n * CAP);

        float a0 = 0.f, a1 = 0.f;
        // tier 1: slots 0..7, unconditional ds_reads (clamped), masked fma
        {
            int4 sA = sp4[0], sB = sp4[1];
            int t0 = ((0 < d) ? sA.x : nb) - nb, t1 = ((1 < d) ? sA.y : nb) - nb;
            int t2 = ((2 < d) ? sA.z : nb) - nb, t3 = ((3 < d) ? sA.w : nb) - nb;
            int t4 = ((4 < d) ? sB.x : nb) - nb, t5 = ((5 < d) ? sB.y : nb) - nb;
            int t6 = ((6 < d) ? sB.z : nb) - nb, t7 = ((7 < d) ? sB.w : nb) - nb;
            unsigned w0 = sxb[t0 * 8 + ln], w1 = sxb[t1 * 8 + ln];
            unsigned w2 = sxb[t2 * 8 + ln], w3 = sxb[t3 * 8 + ln];
            unsigned w4 = sxb[t4 * 8 + ln], w5 = sxb[t5 * 8 + ln];
            unsigned w6 = sxb[t6 * 8 + ln], w7 = sxb[t7 * 8 + ln];
            #define ACC(W, K)                                           \
                { float m = (K < d) ? 1.f : 0.f;                        \
                  a0 = fmaf(m, bflo(W), a0); a1 = fmaf(m, bfhi(W), a1); }
            ACC(w0, 0) ACC(w1, 1) ACC(w2, 2) ACC(w3, 3)
            ACC(w4, 4) ACC(w5, 5) ACC(w6, 6) ACC(w7, 7)
            #undef ACC
        }
        // tier 2: slots 8..31, rare (P(deg>8) ~ 7%)
        if (d > 8) {
            #pragma unroll
            for (int t = 0; t < 3; ++t) {
                int base = 8 + t * 8;
                int4 sC = sp4[2 + 2 * t], sD = sp4[3 + 2 * t];
                int t0 = ((base + 0 < d) ? sC.x : nb) - nb, t1 = ((base + 1 < d) ? sC.y : nb) - nb;
                int t2 = ((base + 2 < d) ? sC.z : nb) - nb, t3 = ((base + 3 < d) ? sC.w : nb) - nb;
                int t4 = ((base + 4 < d) ? sD.x : nb) - nb, t5 = ((base + 5 < d) ? sD.y : nb) - nb;
                int t6 = ((base + 6 < d) ? sD.z : nb) - nb, t7 = ((base + 7 < d) ? sD.w : nb) - nb;
                unsigned w0 = sxb[t0 * 8 + ln], w1 = sxb[t1 * 8 + ln];
                unsigned w2 = sxb[t2 * 8 + ln], w3 = sxb[t3 * 8 + ln];
                unsigned w4 = sxb[t4 * 8 + ln], w5 = sxb[t5 * 8 + ln];
                unsigned w6 = sxb[t6 * 8 + ln], w7 = sxb[t7 * 8 + ln];
                #define ACC2(W, K)                                          \
                    { float m = (base + K < d) ? 1.f : 0.f;                 \
                      a0 = fmaf(m, bflo(W), a0); a1 = fmaf(m, bfhi(W), a1); }
                ACC2(w0, 0) ACC2(w1, 1) ACC2(w2, 2) ACC2(w3, 3)
                ACC2(w4, 4) ACC2(w5, 5) ACC2(w6, 6) ACC2(w7, 7)
                #undef ACC2
            }
        }
        reinterpret_cast<unsigned*>(xa_bf)[(size_t)n * 64 + oct * 8 + ln] = pack2(a0, a1);
    }
}

// -------------------------------------------------------------------------
// k_gemm: TMG=256 rows/block, 512 threads (8 waves). B fragments (WT) loaded
// ONCE per wave into registers (bfrag[4][8] = 128 VGPRs) -- kills the serial
// per-MFMA L2 WT reload that made the 32-VGPR version latency-bound.
// Wave w: col-half = w&1 (4 col-tiles), row-tiles (w>>1)*4 .. +3.
// -------------------------------------------------------------------------
constexpr int TMG         = 256;
constexpr int GEMM_BLOCKS = (N_NODES + TMG - 1) / TMG;      // 196

__global__ __launch_bounds__(512, 2) void k_gemm(
    const float* __restrict__ x,
    const unsigned short* __restrict__ xa_bf,
    const unsigned short* __restrict__ WT,
    const float* __restrict__ bias,
    float* __restrict__ out)
{
    // A-tile: 256 rows x 256 k bf16, row stride 512B, XOR-swizzle (r&7)<<4
    __shared__ unsigned char Ab[TMG * 512];    // 128 KB

    const int tid  = threadIdx.x;
    const int row0 = blockIdx.x * TMG;

    // ---- stage x rows (k = 0..127): f32 -> bf16 pack ----
    #pragma unroll
    for (int i = 0; i < 16; ++i) {
        int idx = tid + i * 512;               // 8192 float4 chunks
        int r = idx >> 5, q = idx & 31;
        int n = row0 + r;
        float4 v = make_float4(0.f, 0.f, 0.f, 0.f);
        if (n < N_NODES) v = reinterpret_cast<const float4*>(x)[(size_t)n * 32 + q];
        int byte = (r * 512 + q * 8) ^ ((r & 7) << 4);
        *reinterpret_cast<u32x2*>(&Ab[byte]) = u32x2{pack2(v.x, v.y), pack2(v.z, v.w)};
    }

    // ---- stage xa rows (k = 128..255): already bf16 ----
    #pragma unroll
    for (int i = 0; i < 16; ++i) {
        int idx = tid + i * 512;               // 8192 8B chunks
        int r = idx >> 5, q = idx & 31;
        int n = row0 + r;
        u32x2 pk{0u, 0u};
        if (n < N_NODES)
            pk = *reinterpret_cast<const u32x2*>(&xa_bf[(size_t)n * 128 + q * 4]);
        int byte = (r * 512 + 256 + q * 8) ^ ((r & 7) << 4);
        *reinterpret_cast<u32x2*>(&Ab[byte]) = pk;
    }

    // ---- B fragments into registers (issues while stage drains) ----
    const int lane = tid & 63;
    const int w    = tid >> 6;
    const int ct0  = (w & 1) * 4;
    const int rtb  = (w >> 1) * 4;

    short8 bfrag[4][8];                        // [cti][ks], 128 VGPRs
    #pragma unroll
    for (int cti = 0; cti < 4; ++cti) {
        int c = (ct0 + cti) * 16 + (lane & 15);
        const short8* bp = reinterpret_cast<const short8*>(WT + (size_t)c * 256)
                           + (lane >> 4);
        #pragma unroll
        for (int ks = 0; ks < 8; ++ks) bfrag[cti][ks] = bp[ks * 4];
    }
    __syncthreads();

    // ---- 4 row-tiles x 4 col-tiles of 16x16x(K=256) ----
    #pragma unroll
    for (int j = 0; j < 4; ++j) {
        int rt = rtb + j;
        int r  = rt * 16 + (lane & 15);
        int kb = (lane >> 4) * 16;
        short8 a[8];
        #pragma unroll
        for (int ks = 0; ks < 8; ++ks) {
            int byte = (r * 512 + ks * 64 + kb) ^ ((r & 7) << 4);
            a[ks] = *reinterpret_cast<const short8*>(&Ab[byte]);
        }
        #pragma unroll
        for (int cti = 0; cti < 4; ++cti) {
            f32x4 acc = {0.f, 0.f, 0.f, 0.f};
            #pragma unroll
            for (int ks = 0; ks < 8; ++ks)
                acc = __builtin_amdgcn_mfma_f32_16x16x32_bf16(a[ks], bfrag[cti][ks],
                                                              acc, 0, 0, 0);
            int c  = (ct0 + cti) * 16 + (lane & 15);
            float bv = (float)G_GRP * bias[c];
            #pragma unroll
            for (int ii = 0; ii < 4; ++ii) {
                int rr = row0 + rt * 16 + (lane >> 4) * 4 + ii;  // C/D row map
                if (rr < N_NODES) out[(size_t)rr * C_OUT + c] = acc[ii] + bv;
            }
        }
    }
}

extern "C" void kernel_launch(void* const* d_in, const int* in_sizes, int n_in,
                              void* d_out, int out_size, void* d_ws, size_t ws_size,
                              hipStream_t stream)
{
    const float* x     = (const float*)d_in[0];
    // d_in[1] = W_group -- cancels (softmax rows sum to 1)
    const float* Wself = (const float*)d_in[2];
    const float* Wnbr  = (const float*)d_in[3];
    const float* bias  = (const float*)d_in[4];
    const int*   eidx  = (const int*)d_in[5];
    // d_in[6] = batch, d_in[7] = group_ptr -- unused after collapse

    const int* src = eidx;
    const int* dst = eidx + E_EDGES;

    // Workspace: cnt[N] + buckets[N*CAP] + WT[32768] u16 + xa_bf[N*128] u16
    int* cnt     = (int*)d_ws;
    int* buckets = cnt + N_NODES;
    unsigned short* WT    = (unsigned short*)(buckets + (size_t)N_NODES * CAP);
    unsigned short* xa_bf = WT + (size_t)C_OUT * 256;

    float* out = (float*)d_out;

    k_zero<<<CNT_BLKS, 256, 0, stream>>>(cnt);

    k_fill_prep<<<EDGE_BLOCKS + WT_BLKS, 256, 0, stream>>>(
        src, dst, cnt, buckets, Wself, Wnbr, WT);

    k_gather<<<GATHER_BLOCKS, 512, 0, stream>>>(x, cnt, buckets, xa_bf);

    k_gemm<<<GEMM_BLOCKS, 512, 0, stream>>>(x, xa_bf, WT, bias, out);
}